// Round 13
// baseline (234.569 us; speedup 1.0000x reference)
//
#include <hip/hip_runtime.h>
#include <hip/hip_bf16.h>

#define BSZ 2
#define C 256
#define NH 8
#define DIM 32
#define LSEQ 30720
#define ROWS (BSZ*LSEQ)
#define FF 1024
#define NCHUNK 120
#define CHS 256
#define MCHUNK (ROWS/2)

typedef __attribute__((ext_vector_type(8))) short bf16x8;
typedef __attribute__((ext_vector_type(4))) float f32x4;

__device__ __forceinline__ float phi_elu1(float v) { return v > 0.f ? v + 1.f : __expf(v); }

// x * sigmoid(1.702 x)  (exp2 form; 1.702*log2e = 2.4554224).
// |err vs erf-gelu| <= ~0.01 for |x|<2.5 (ff inputs ~N(0,0.8)), <=0.02 worst.
// NaN-free for finite x: exp2 overflow -> rcp(inf)=0 -> x*0 = +-0.
__device__ __forceinline__ float fast_gelu(float x) {
    float q = __builtin_amdgcn_exp2f(-2.4554224f * x);
    return x * __builtin_amdgcn_rcpf(1.f + q);
}

// round-to-nearest-even f32 -> bf16 bits (finite inputs)
__device__ __forceinline__ unsigned short f2bf(float f) {
    unsigned int u = __float_as_uint(f);
    u += 0x7fffu + ((u >> 16) & 1u);
    return (unsigned short)(u >> 16);
}
__device__ __forceinline__ float bf2f(unsigned short u) {
    return __uint_as_float(((unsigned int)u) << 16);
}
__device__ __forceinline__ unsigned int pack2bf(float a, float b) {
    return (unsigned int)f2bf(a) | ((unsigned int)f2bf(b) << 16);
}

// async global->LDS, 16B per lane. LDS dest is wave-uniform base + lane*16.
__device__ __forceinline__ void gload_lds16(const unsigned short* g, unsigned short* l) {
    __builtin_amdgcn_global_load_lds(
        (const __attribute__((address_space(1))) unsigned int*)g,
        (__attribute__((address_space(3))) unsigned int*)l, 16, 0, 0);
}

// ---------------- K0: weights fp32 -> bf16 ----------------
__global__ __launch_bounds__(256) void k0_cvt(
        const float* __restrict__ W1, const float* __restrict__ W2,
        unsigned short* __restrict__ W1b, unsigned short* __restrict__ W2b) {
    const int i = blockIdx.x * 256 + threadIdx.x;   // 262144 total
    W1b[i] = f2bf(W1[i]);
    W2b[i] = f2bf(W2[i]);
}

// ---------------- K1 (MFMA): projection + partial KV(32x32) + Ksum per (b,h,chunk) ----------------
__global__ __launch_bounds__(256) void k1_kv_partial_mfma(
        const float* __restrict__ x, const float* __restrict__ Wkqv,
        float* __restrict__ part) {
    __shared__ __align__(16) unsigned short KsT[32*264];
    __shared__ __align__(16) unsigned short VsT[32*264];
    __shared__ __align__(16) float red[4][32][33];
    __shared__ __align__(16) float ksr[4][32];
    const int t = threadIdx.x;
    const int w = t >> 6, lane = t & 63;
    const int g = lane >> 4, m = lane & 15;
    const int bh = blockIdx.x, chunk = blockIdx.y;
    const int b = bh >> 3, head = bh & 7;
    const size_t rowbase = (size_t)b*LSEQ + (size_t)chunk*CHS;

    bf16x8 wk[2], wv[2];
    #pragma unroll
    for (int half = 0; half < 2; ++half) {
        const float* kp = Wkqv + (half*16 + m)*DIM + g*8;   // K rows 0..31
        const float* vp = kp + 2*DIM*DIM;                   // V rows 64..95
        float4 ka = *reinterpret_cast<const float4*>(kp);
        float4 kb = *reinterpret_cast<const float4*>(kp + 4);
        float4 va = *reinterpret_cast<const float4*>(vp);
        float4 vb = *reinterpret_cast<const float4*>(vp + 4);
        wk[half][0]=(short)f2bf(ka.x); wk[half][1]=(short)f2bf(ka.y);
        wk[half][2]=(short)f2bf(ka.z); wk[half][3]=(short)f2bf(ka.w);
        wk[half][4]=(short)f2bf(kb.x); wk[half][5]=(short)f2bf(kb.y);
        wk[half][6]=(short)f2bf(kb.z); wk[half][7]=(short)f2bf(kb.w);
        wv[half][0]=(short)f2bf(va.x); wv[half][1]=(short)f2bf(va.y);
        wv[half][2]=(short)f2bf(va.z); wv[half][3]=(short)f2bf(va.w);
        wv[half][4]=(short)f2bf(vb.x); wv[half][5]=(short)f2bf(vb.y);
        wv[half][6]=(short)f2bf(vb.z); wv[half][7]=(short)f2bf(vb.w);
    }
    const f32x4 zac = {0.f, 0.f, 0.f, 0.f};
    f32x4 ks0 = zac, ks1 = zac;
    #pragma unroll
    for (int sg = 0; sg < 4; ++sg) {
        const int sl = w*64 + sg*16 + m;
        const float* xp = x + (rowbase + sl)*C + head*DIM + g*8;
        float4 xa = *reinterpret_cast<const float4*>(xp);
        float4 xc = *reinterpret_cast<const float4*>(xp + 4);
        bf16x8 xf;
        xf[0]=(short)f2bf(xa.x); xf[1]=(short)f2bf(xa.y);
        xf[2]=(short)f2bf(xa.z); xf[3]=(short)f2bf(xa.w);
        xf[4]=(short)f2bf(xc.x); xf[5]=(short)f2bf(xc.y);
        xf[6]=(short)f2bf(xc.z); xf[7]=(short)f2bf(xc.w);
        f32x4 kt0 = __builtin_amdgcn_mfma_f32_16x16x32_bf16(wk[0], xf, zac, 0, 0, 0);
        f32x4 kt1 = __builtin_amdgcn_mfma_f32_16x16x32_bf16(wk[1], xf, zac, 0, 0, 0);
        f32x4 vt0 = __builtin_amdgcn_mfma_f32_16x16x32_bf16(wv[0], xf, zac, 0, 0, 0);
        f32x4 vt1 = __builtin_amdgcn_mfma_f32_16x16x32_bf16(wv[1], xf, zac, 0, 0, 0);
        #pragma unroll
        for (int r = 0; r < 4; ++r) {
            unsigned short u0 = f2bf(phi_elu1(kt0[r]));
            unsigned short u1 = f2bf(phi_elu1(kt1[r]));
            KsT[(4*g+r)*264 + sl]    = u0;
            KsT[(16+4*g+r)*264 + sl] = u1;
            ks0[r] += bf2f(u0);
            ks1[r] += bf2f(u1);
            VsT[(4*g+r)*264 + sl]    = f2bf(vt0[r]);
            VsT[(16+4*g+r)*264 + sl] = f2bf(vt1[r]);
        }
    }
    #pragma unroll
    for (int mk = 8; mk >= 1; mk >>= 1) {
        #pragma unroll
        for (int r = 0; r < 4; ++r) {
            ks0[r] += __shfl_xor(ks0[r], mk, 64);
            ks1[r] += __shfl_xor(ks1[r], mk, 64);
        }
    }
    if (m == 0) {
        #pragma unroll
        for (int r = 0; r < 4; ++r) {
            ksr[w][4*g + r]      = ks0[r];
            ksr[w][16 + 4*g + r] = ks1[r];
        }
    }
    __syncthreads();
    f32x4 acc[2][2] = {};
    #pragma unroll
    for (int ss = 0; ss < 2; ++ss) {
        const int s0 = w*64 + ss*32 + g*8;
        bf16x8 aK0 = *reinterpret_cast<const bf16x8*>(&KsT[m*264 + s0]);
        bf16x8 aK1 = *reinterpret_cast<const bf16x8*>(&KsT[(16+m)*264 + s0]);
        bf16x8 bV0 = *reinterpret_cast<const bf16x8*>(&VsT[m*264 + s0]);
        bf16x8 bV1 = *reinterpret_cast<const bf16x8*>(&VsT[(16+m)*264 + s0]);
        acc[0][0] = __builtin_amdgcn_mfma_f32_16x16x32_bf16(aK0, bV0, acc[0][0], 0, 0, 0);
        acc[0][1] = __builtin_amdgcn_mfma_f32_16x16x32_bf16(aK0, bV1, acc[0][1], 0, 0, 0);
        acc[1][0] = __builtin_amdgcn_mfma_f32_16x16x32_bf16(aK1, bV0, acc[1][0], 0, 0, 0);
        acc[1][1] = __builtin_amdgcn_mfma_f32_16x16x32_bf16(aK1, bV1, acc[1][1], 0, 0, 0);
    }
    #pragma unroll
    for (int i = 0; i < 2; ++i)
        #pragma unroll
        for (int j = 0; j < 2; ++j)
            #pragma unroll
            for (int r = 0; r < 4; ++r)
                red[w][i*16 + 4*g + r][j*16 + m] = acc[i][j][r];
    __syncthreads();
    float* pb = part + ((size_t)bh*NCHUNK + chunk)*1056;
    {
        const int d = t >> 3, e0 = (t & 7)*4;
        float4 sum;
        sum.x = red[0][d][e0+0]+red[1][d][e0+0]+red[2][d][e0+0]+red[3][d][e0+0];
        sum.y = red[0][d][e0+1]+red[1][d][e0+1]+red[2][d][e0+1]+red[3][d][e0+1];
        sum.z = red[0][d][e0+2]+red[1][d][e0+2]+red[2][d][e0+2]+red[3][d][e0+2];
        sum.w = red[0][d][e0+3]+red[1][d][e0+3]+red[2][d][e0+3]+red[3][d][e0+3];
        *reinterpret_cast<float4*>(pb + d*32 + e0) = sum;
    }
    if (t < 32) {
        pb[1024 + t] = ksr[0][t] + ksr[1][t] + ksr[2][t] + ksr[3][t];
    }
}

// ---------------- K2: deterministic reduce ----------------
__global__ __launch_bounds__(256) void k2_kv_reduce(
        const float* __restrict__ part, float* __restrict__ kv) {
    const int bh = blockIdx.x, t = threadIdx.x;
    for (int i = t; i < 1056; i += 256) {
        float s = 0.f;
        for (int c2 = 0; c2 < NCHUNK; ++c2)
            s += part[((size_t)bh*NCHUNK + c2)*1056 + i];
        kv[bh*1056 + i] = s;
    }
}

// ---------------- K3 (MFMA): Q-proj + attn, residual + LN1 -> xb ----------------
__global__ __launch_bounds__(256) void k3_attn_ln1_mfma(
        const float* __restrict__ x, const float* __restrict__ Wkqv,
        const float* __restrict__ kv, const float* __restrict__ g1,
        const float* __restrict__ be1, unsigned short* __restrict__ xb) {
    __shared__ __align__(16) unsigned short wq[32*40];
    __shared__ __align__(16) unsigned short kvt[NH*32*40];
    __shared__ __align__(16) float ksm[NH*32];
    __shared__ __align__(16) float gl[C], bl[C];
    __shared__ __align__(16) unsigned short qld[4][2][16*40];
    const int t = threadIdx.x;
    const int wid = t >> 6, lane = t & 63;
    const int g = lane >> 4, m = lane & 15;
    const int row0 = blockIdx.x * 64;
    const int b = row0 / LSEQ;
    for (int idx = t; idx < 1024; idx += 256) {
        int e = idx >> 5, d = idx & 31;
        wq[e*40 + d] = f2bf(Wkqv[1024 + idx]);
    }
    for (int idx = t; idx < NH*1024; idx += 256) {
        int h = idx >> 10, rem = idx & 1023;
        int d = rem >> 5, eo = rem & 31;
        kvt[h*1280 + eo*40 + d] = f2bf(kv[(size_t)(b*NH + h)*1056 + rem]);
    }
    {
        int h = t >> 5, d = t & 31;
        ksm[t] = kv[(size_t)(b*NH + h)*1056 + 1024 + d];
        gl[t] = g1[t];
        bl[t] = be1[t];
    }
    __syncthreads();

    const int row = row0 + wid*16 + m;
    f32x4 att[NH][2];
    const f32x4 zacc = {0.f, 0.f, 0.f, 0.f};
    #pragma unroll
    for (int h = 0; h < NH; ++h) {
        const float* xp = x + (size_t)row*C + h*32 + g*8;
        float4 xa = *reinterpret_cast<const float4*>(xp);
        float4 xc = *reinterpret_cast<const float4*>(xp + 4);
        bf16x8 xfrag;
        xfrag[0] = (short)f2bf(xa.x); xfrag[1] = (short)f2bf(xa.y);
        xfrag[2] = (short)f2bf(xa.z); xfrag[3] = (short)f2bf(xa.w);
        xfrag[4] = (short)f2bf(xc.x); xfrag[5] = (short)f2bf(xc.y);
        xfrag[6] = (short)f2bf(xc.z); xfrag[7] = (short)f2bf(xc.w);
        bf16x8 wf0 = *reinterpret_cast<const bf16x8*>(&wq[m*40 + g*8]);
        bf16x8 wf1 = *reinterpret_cast<const bf16x8*>(&wq[(16+m)*40 + g*8]);
        f32x4 q0 = __builtin_amdgcn_mfma_f32_16x16x32_bf16(wf0, xfrag, zacc, 0, 0, 0);
        f32x4 q1 = __builtin_amdgcn_mfma_f32_16x16x32_bf16(wf1, xfrag, zacc, 0, 0, 0);
        #pragma unroll
        for (int r = 0; r < 4; ++r) { q0[r] = phi_elu1(q0[r]); q1[r] = phi_elu1(q1[r]); }
        f32x4 ks0 = *reinterpret_cast<const f32x4*>(&ksm[h*32 + g*4]);
        f32x4 ks1 = *reinterpret_cast<const f32x4*>(&ksm[h*32 + 16 + g*4]);
        float zp = q0[0]*ks0[0] + q0[1]*ks0[1] + q0[2]*ks0[2] + q0[3]*ks0[3]
                 + q1[0]*ks1[0] + q1[1]*ks1[1] + q1[2]*ks1[2] + q1[3]*ks1[3];
        zp += __shfl_xor(zp, 16, 64);
        zp += __shfl_xor(zp, 32, 64);
        const float Z = 1.f / (zp + 1e-6f);
        unsigned short* slot = &qld[wid][h & 1][0];
        *reinterpret_cast<uint2*>(&slot[m*40 + g*4]) =
            make_uint2(pack2bf(q0[0], q0[1]), pack2bf(q0[2], q0[3]));
        *reinterpret_cast<uint2*>(&slot[m*40 + 16 + g*4]) =
            make_uint2(pack2bf(q1[0], q1[1]), pack2bf(q1[2], q1[3]));
        __builtin_amdgcn_wave_barrier();
        bf16x8 qrow = *reinterpret_cast<const bf16x8*>(&slot[m*40 + g*8]);
        __builtin_amdgcn_wave_barrier();
        bf16x8 kf0 = *reinterpret_cast<const bf16x8*>(&kvt[h*1280 + m*40 + g*8]);
        bf16x8 kf1 = *reinterpret_cast<const bf16x8*>(&kvt[h*1280 + (16+m)*40 + g*8]);
        f32x4 a0 = __builtin_amdgcn_mfma_f32_16x16x32_bf16(kf0, qrow, zacc, 0, 0, 0);
        f32x4 a1 = __builtin_amdgcn_mfma_f32_16x16x32_bf16(kf1, qrow, zacc, 0, 0, 0);
        #pragma unroll
        for (int r = 0; r < 4; ++r) { a0[r] *= Z; a1[r] *= Z; }
        att[h][0] = a0;
        att[h][1] = a1;
    }
    float s1 = 0.f, s2 = 0.f;
    #pragma unroll
    for (int h = 0; h < NH; ++h) {
        #pragma unroll
        for (int n = 0; n < 2; ++n) {
            const int c0 = h*32 + n*16 + g*4;
            float4 xr = *reinterpret_cast<const float4*>(x + (size_t)row*C + c0);
            f32x4 v = att[h][n];
            v[0] += xr.x; v[1] += xr.y; v[2] += xr.z; v[3] += xr.w;
            att[h][n] = v;
            s1 += v[0] + v[1] + v[2] + v[3];
            s2 += v[0]*v[0] + v[1]*v[1] + v[2]*v[2] + v[3]*v[3];
        }
    }
    s1 += __shfl_xor(s1, 16, 64); s1 += __shfl_xor(s1, 32, 64);
    s2 += __shfl_xor(s2, 16, 64); s2 += __shfl_xor(s2, 32, 64);
    const float mean = s1 * (1.f/C);
    const float var  = s2 * (1.f/C) - mean*mean;
    const float rs = rsqrtf(var + 1e-5f);
    #pragma unroll
    for (int h = 0; h < NH; ++h) {
        #pragma unroll
        for (int n = 0; n < 2; ++n) {
            const int c0 = h*32 + n*16 + g*4;
            f32x4 gv = *reinterpret_cast<const f32x4*>(&gl[c0]);
            f32x4 bv = *reinterpret_cast<const f32x4*>(&bl[c0]);
            f32x4 v = att[h][n];
            float o0 = (v[0]-mean)*rs*gv[0] + bv[0];
            float o1 = (v[1]-mean)*rs*gv[1] + bv[1];
            float o2 = (v[2]-mean)*rs*gv[2] + bv[2];
            float o3 = (v[3]-mean)*rs*gv[3] + bv[3];
            *reinterpret_cast<uint2*>(xb + (size_t)row*C + c0) =
                make_uint2(pack2bf(o0, o1), pack2bf(o2, o3));
        }
    }
}

// ---------------- K4: MFMA GEMM1, 128x128 tile, XCD swizzle, LDS-bounce epilogue ----------------
// Epilogue: gelu'd bf16 -> LDS [128][136] (16B-aligned rows), barrier, then
// 2 threads/row copy out as 8x16B coalesced stores (replaces 64 scalar 2B
// stores/thread -> 8x fewer wave-store transactions, one store base + imm offsets).
__global__ __launch_bounds__(256) void k4_ffn1_mfma(
        const unsigned short* __restrict__ A, const unsigned short* __restrict__ B,
        const float* __restrict__ b1, unsigned short* __restrict__ c1, int mbase) {
    __shared__ __align__(16) unsigned short smem4[128*136];   // 34.8 KB; loop uses first 32 KB
    unsigned short* As = smem4;            // 8192 ushorts
    unsigned short* Bs = smem4 + 8192;     // 8192 ushorts
    const int t = threadIdx.x;
    const int wid = t >> 6, lane = t & 63;
    const int wr = wid >> 1, wc = wid & 1;
    const int chunkw = gridDim.x >> 3;                      // blocks per XCD
    const int swz = (blockIdx.x & 7) * chunkw + (blockIdx.x >> 3);
    const int rowp = swz >> 3, colb = swz & 7;
    const int m0 = mbase + rowp*128;
    const int n0 = colb*128;
    f32x4 acc[4][4] = {};
    for (int kt = 0; kt < C/64; ++kt) {
        const int k0 = kt*64;
        #pragma unroll
        for (int i = 0; i < 4; ++i) {
            const int seg = i*256 + t;
            const int row = seg >> 3, jd = seg & 7;
            const int js = jd ^ (row & 7);
            gload_lds16(A + (size_t)(m0+row)*C + k0 + js*8, &As[(i*256 + wid*64)*8]);
            gload_lds16(B + (size_t)(n0+row)*C + k0 + js*8, &Bs[(i*256 + wid*64)*8]);
        }
        __syncthreads();
        #pragma unroll
        for (int kk = 0; kk < 2; ++kk) {
            bf16x8 af[4], bfr[4];
            #pragma unroll
            for (int m = 0; m < 4; ++m) {
                const int row = wr*64 + m*16 + (lane & 15);
                const int j = (kk*4 + (lane >> 4)) ^ (row & 7);
                af[m] = *reinterpret_cast<const bf16x8*>(&As[row*64 + j*8]);
            }
            #pragma unroll
            for (int n = 0; n < 4; ++n) {
                const int row = wc*64 + n*16 + (lane & 15);
                const int j = (kk*4 + (lane >> 4)) ^ (row & 7);
                bfr[n] = *reinterpret_cast<const bf16x8*>(&Bs[row*64 + j*8]);
            }
            #pragma unroll
            for (int m = 0; m < 4; ++m)
                #pragma unroll
                for (int n = 0; n < 4; ++n)
                    acc[m][n] = __builtin_amdgcn_mfma_f32_16x16x32_bf16(af[m], bfr[n], acc[m][n], 0, 0, 0);
        }
        __syncthreads();   // also fences As/Bs before the epi overlay below
    }
    const int r4 = lane >> 4, cc = lane & 15;
    float b1v[4];
    #pragma unroll
    for (int n = 0; n < 4; ++n) b1v[n] = b1[n0 + wc*64 + n*16 + cc];
    unsigned short* epi = smem4;           // [128][136] overlay
    #pragma unroll
    for (int m = 0; m < 4; ++m) {
        #pragma unroll
        for (int r = 0; r < 4; ++r) {
            const int erow = wr*64 + m*16 + r4*4 + r;
            #pragma unroll
            for (int n = 0; n < 4; ++n) {
                float f = acc[m][n][r] + b1v[n];
                epi[erow*136 + wc*64 + n*16 + cc] = f2bf(fast_gelu(f));
            }
        }
    }
    __syncthreads();
    {
        const int row = t >> 1, colh = (t & 1) << 6;
        const unsigned short* src = epi + row*136 + colh;
        unsigned short* dst = c1 + (size_t)(rowp*128 + row)*FF + n0 + colh;
        #pragma unroll
        for (int q = 0; q < 8; ++q)
            *reinterpret_cast<bf16x8*>(dst + q*8) =
                *reinterpret_cast<const bf16x8*>(src + q*8);
    }
}

// ---------------- K5: MFMA GEMM2 + residual + LN2 fused, 2-phase prefetch ----------------
__global__ __launch_bounds__(256) void k5_ffn2_ln(
        const unsigned short* __restrict__ A, const unsigned short* __restrict__ B,
        const float* __restrict__ b2, const unsigned short* __restrict__ xb,
        const float* __restrict__ g2, const float* __restrict__ be2,
        float* __restrict__ out, int mbase) {
    __shared__ __align__(16) unsigned short smem[40960];   // 80 KB
    unsigned short* As0 = smem;
    unsigned short* As1 = smem + 4096;
    unsigned short* Bs0 = smem + 8192;
    unsigned short* Bs1 = smem + 8192 + 16384;
    const int t = threadIdx.x;
    const int wid = t >> 6, lane = t & 63;
    const int lm0 = blockIdx.x*64;
    f32x4 acc[4][4] = {};

    #pragma unroll
    for (int i = 0; i < 2; ++i) {
        const int row = (i*256 + t) >> 3, jd = (i*256 + t) & 7;
        const int js = jd ^ (row & 7);
        gload_lds16(A + (size_t)(lm0+row)*FF + js*8, &As0[(i*256 + wid*64)*8]);
    }
    #pragma unroll
    for (int i = 0; i < 8; ++i) {
        const int row = (i*256 + t) >> 3, jd = (i*256 + t) & 7;
        const int js = jd ^ (row & 7);
        gload_lds16(B + (size_t)row*FF + js*8, &Bs0[(i*256 + wid*64)*8]);
    }
    __syncthreads();
    for (int kt = 0; kt < FF/64; ++kt) {
        const int cur = kt & 1;
        unsigned short* Asc = cur ? As1 : As0;
        unsigned short* Bsc = cur ? Bs1 : Bs0;
        if (kt < FF/64 - 1) {
            unsigned short* Asn = cur ? As0 : As1;
            unsigned short* Bsn = cur ? Bs0 : Bs1;
            const int k0n = (kt+1)*64;
            #pragma unroll
            for (int i = 0; i < 2; ++i) {
                const int row = (i*256 + t) >> 3, jd = (i*256 + t) & 7;
                const int js = jd ^ (row & 7);
                gload_lds16(A + (size_t)(lm0+row)*FF + k0n + js*8, &Asn[(i*256 + wid*64)*8]);
            }
            #pragma unroll
            for (int i = 0; i < 8; ++i) {
                const int row = (i*256 + t) >> 3, jd = (i*256 + t) & 7;
                const int js = jd ^ (row & 7);
                gload_lds16(B + (size_t)row*FF + k0n + js*8, &Bsn[(i*256 + wid*64)*8]);
            }
        }
        #pragma unroll
        for (int kk = 0; kk < 2; ++kk) {
            bf16x8 af[4], bfr[4];
            #pragma unroll
            for (int m = 0; m < 4; ++m) {
                const int row = m*16 + (lane & 15);
                const int j = (kk*4 + (lane >> 4)) ^ (row & 7);
                af[m] = *reinterpret_cast<const bf16x8*>(&Asc[row*64 + j*8]);
            }
            #pragma unroll
            for (int n = 0; n < 4; ++n) {
                const int row = wid*64 + n*16 + (lane & 15);
                const int j = (kk*4 + (lane >> 4)) ^ (row & 7);
                bfr[n] = *reinterpret_cast<const bf16x8*>(&Bsc[row*64 + j*8]);
            }
            #pragma unroll
            for (int m = 0; m < 4; ++m)
                #pragma unroll
                for (int n = 0; n < 4; ++n)
                    acc[m][n] = __builtin_amdgcn_mfma_f32_16x16x32_bf16(af[m], bfr[n], acc[m][n], 0, 0, 0);
        }
        if (kt < FF/64 - 1) __syncthreads();
    }
    float* red1 = (float*)smem;
    float* red2 = (float*)smem + 256;
    float* mear = (float*)smem + 512;
    float* rsr  = (float*)smem + 576;
    const int r4 = lane >> 4, cc = lane & 15;
    float b2v[4], g2v[4], be2v[4];
    #pragma unroll
    for (int n = 0; n < 4; ++n) {
        const int gcol = wid*64 + n*16 + cc;
        b2v[n] = b2[gcol]; g2v[n] = g2[gcol]; be2v[n] = be2[gcol];
    }
    float s1[4][4] = {}, s2[4][4] = {};
    #pragma unroll
    for (int m = 0; m < 4; ++m) {
        #pragma unroll
        for (int n = 0; n < 4; ++n) {
            const int gcol = wid*64 + n*16 + cc;
            #pragma unroll
            for (int r = 0; r < 4; ++r) {
                const size_t grow = (size_t)(mbase + lm0 + m*16 + r4*4 + r);
                float v = acc[m][n][r] + b2v[n] + bf2f(xb[grow*C + gcol]);
                acc[m][n][r] = v;
                s1[m][r] += v;
                s2[m][r] += v*v;
            }
        }
    }
    #pragma unroll
    for (int m = 0; m < 4; ++m) {
        #pragma unroll
        for (int r = 0; r < 4; ++r) {
            float a = s1[m][r], bb = s2[m][r];
            #pragma unroll
            for (int mk = 8; mk >= 1; mk >>= 1) {
                a  += __shfl_xor(a,  mk, 16);
                bb += __shfl_xor(bb, mk, 16);
            }
            if (cc == 0) {
                red1[wid*64 + m*16 + r4*4 + r] = a;
                red2[wid*64 + m*16 + r4*4 + r] = bb;
            }
        }
    }
    __syncthreads();
    if (t < 64) {
        float a  = red1[t]+red1[64+t]+red1[128+t]+red1[192+t];
        float bb = red2[t]+red2[64+t]+red2[128+t]+red2[192+t];
        float mean = a * (1.f/C);
        float var  = bb * (1.f/C) - mean*mean;
        mear[t] = mean;
        rsr[t]  = rsqrtf(var + 1e-5f);
    }
    __syncthreads();
    #pragma unroll
    for (int m = 0; m < 4; ++m) {
        #pragma unroll
        for (int r = 0; r < 4; ++r) {
            const int rl = m*16 + r4*4 + r;
            const float mu = mear[rl], rs = rsr[rl];
            const size_t grow = (size_t)(mbase + lm0 + rl);
            #pragma unroll
            for (int n = 0; n < 4; ++n) {
                const int gcol = wid*64 + n*16 + cc;
                out[grow*C + gcol] = (acc[m][n][r] - mu)*rs*g2v[n] + be2v[n];
            }
        }
    }
}

extern "C" void kernel_launch(void* const* d_in, const int* in_sizes, int n_in,
                              void* d_out, int out_size, void* d_ws, size_t ws_size,
                              hipStream_t stream) {
    const float* x    = (const float*)d_in[0];
    const float* Wkqv = (const float*)d_in[1];
    const float* W1   = (const float*)d_in[2];
    const float* b1   = (const float*)d_in[3];
    const float* W2   = (const float*)d_in[4];
    const float* b2   = (const float*)d_in[5];
    const float* g1   = (const float*)d_in[6];
    const float* be1  = (const float*)d_in[7];
    const float* g2   = (const float*)d_in[8];
    const float* be2  = (const float*)d_in[9];
    float* out = (float*)d_out;

    // ws layout (bytes):
    //   kv @ 0 | W1b @ 128K | W2b @ 640K | part @ 2M | xb @ 12M | c1 @ 48M
    // Full-M path needs 48M + ROWS*FF*2 = 176,160,768 B; else 2-chunk (111 MB).
    char* wsb = (char*)d_ws;
    float* kv            = (float*)(wsb);
    unsigned short* W1b  = (unsigned short*)(wsb + (131072));
    unsigned short* W2b  = (unsigned short*)(wsb + (655360));
    float* part          = (float*)(wsb + ((size_t)2 << 20));
    unsigned short* xb   = (unsigned short*)(wsb + ((size_t)12 << 20));
    unsigned short* c1   = (unsigned short*)(wsb + ((size_t)48 << 20));
    const size_t need_full = ((size_t)48 << 20) + (size_t)ROWS * FF * 2;

    k0_cvt<<<1024, 256, 0, stream>>>(W1, W2, W1b, W2b);
    k1_kv_partial_mfma<<<dim3(16, NCHUNK), 256, 0, stream>>>(x, Wkqv, part);
    k2_kv_reduce<<<16, 256, 0, stream>>>(part, kv);
    k3_attn_ln1_mfma<<<ROWS/64, 256, 0, stream>>>(x, Wkqv, kv, g1, be1, xb);
    if (ws_size >= need_full) {
        k4_ffn1_mfma<<<(ROWS/128)*(FF/128), 256, 0, stream>>>(xb, W1b, b1, c1, 0);
        k5_ffn2_ln<<<ROWS/64, 256, 0, stream>>>(c1, W2b, b2, xb, g2, be2, out, 0);
    } else {
        for (int chunk = 0; chunk < 2; ++chunk) {
            const int mbase = chunk * MCHUNK;
            k4_ffn1_mfma<<<(MCHUNK/128)*(FF/128), 256, 0, stream>>>(xb, W1b, b1, c1, mbase);
            k5_ffn2_ln<<<MCHUNK/64, 256, 0, stream>>>(c1, W2b, b2, xb, g2, be2, out, mbase);
        }
    }
}

// Round 14
// 207.113 us; speedup vs baseline: 1.1326x; 1.1326x over previous
//
#include <hip/hip_runtime.h>
#include <hip/hip_bf16.h>

#define BSZ 2
#define C 256
#define NH 8
#define DIM 32
#define LSEQ 30720
#define ROWS (BSZ*LSEQ)
#define FF 1024
#define NCHUNK 120
#define CHS 256
#define MCHUNK (ROWS/2)

typedef __attribute__((ext_vector_type(8))) short bf16x8;
typedef __attribute__((ext_vector_type(4))) float f32x4;

__device__ __forceinline__ float phi_elu1(float v) { return v > 0.f ? v + 1.f : __expf(v); }

// x * sigmoid(1.702 x)  (exp2 form; 1.702*log2e = 2.4554224).
// |err vs erf-gelu| <= ~0.01 in the occupied range. NaN-free for finite x.
__device__ __forceinline__ float fast_gelu(float x) {
    float q = __builtin_amdgcn_exp2f(-2.4554224f * x);
    return x * __builtin_amdgcn_rcpf(1.f + q);
}

// round-to-nearest-even f32 -> bf16 bits (finite inputs)
__device__ __forceinline__ unsigned short f2bf(float f) {
    unsigned int u = __float_as_uint(f);
    u += 0x7fffu + ((u >> 16) & 1u);
    return (unsigned short)(u >> 16);
}
__device__ __forceinline__ float bf2f(unsigned short u) {
    return __uint_as_float(((unsigned int)u) << 16);
}
__device__ __forceinline__ unsigned int pack2bf(float a, float b) {
    return (unsigned int)f2bf(a) | ((unsigned int)f2bf(b) << 16);
}

// async global->LDS, 16B per lane. LDS dest is wave-uniform base + lane*16.
__device__ __forceinline__ void gload_lds16(const unsigned short* g, unsigned short* l) {
    __builtin_amdgcn_global_load_lds(
        (const __attribute__((address_space(1))) unsigned int*)g,
        (__attribute__((address_space(3))) unsigned int*)l, 16, 0, 0);
}

// ---------------- K0: weights fp32 -> bf16 ----------------
__global__ __launch_bounds__(256) void k0_cvt(
        const float* __restrict__ W1, const float* __restrict__ W2,
        unsigned short* __restrict__ W1b, unsigned short* __restrict__ W2b) {
    const int i = blockIdx.x * 256 + threadIdx.x;   // 262144 total
    W1b[i] = f2bf(W1[i]);
    W2b[i] = f2bf(W2[i]);
}

// ---------------- K1 (MFMA): projection + partial KV(32x32) + Ksum per (b,h,chunk) ----------------
__global__ __launch_bounds__(256) void k1_kv_partial_mfma(
        const float* __restrict__ x, const float* __restrict__ Wkqv,
        float* __restrict__ part) {
    __shared__ __align__(16) unsigned short KsT[32*264];
    __shared__ __align__(16) unsigned short VsT[32*264];
    __shared__ __align__(16) float red[4][32][33];
    __shared__ __align__(16) float ksr[4][32];
    const int t = threadIdx.x;
    const int w = t >> 6, lane = t & 63;
    const int g = lane >> 4, m = lane & 15;
    const int bh = blockIdx.x, chunk = blockIdx.y;
    const int b = bh >> 3, head = bh & 7;
    const size_t rowbase = (size_t)b*LSEQ + (size_t)chunk*CHS;

    bf16x8 wk[2], wv[2];
    #pragma unroll
    for (int half = 0; half < 2; ++half) {
        const float* kp = Wkqv + (half*16 + m)*DIM + g*8;   // K rows 0..31
        const float* vp = kp + 2*DIM*DIM;                   // V rows 64..95
        float4 ka = *reinterpret_cast<const float4*>(kp);
        float4 kb = *reinterpret_cast<const float4*>(kp + 4);
        float4 va = *reinterpret_cast<const float4*>(vp);
        float4 vb = *reinterpret_cast<const float4*>(vp + 4);
        wk[half][0]=(short)f2bf(ka.x); wk[half][1]=(short)f2bf(ka.y);
        wk[half][2]=(short)f2bf(ka.z); wk[half][3]=(short)f2bf(ka.w);
        wk[half][4]=(short)f2bf(kb.x); wk[half][5]=(short)f2bf(kb.y);
        wk[half][6]=(short)f2bf(kb.z); wk[half][7]=(short)f2bf(kb.w);
        wv[half][0]=(short)f2bf(va.x); wv[half][1]=(short)f2bf(va.y);
        wv[half][2]=(short)f2bf(va.z); wv[half][3]=(short)f2bf(va.w);
        wv[half][4]=(short)f2bf(vb.x); wv[half][5]=(short)f2bf(vb.y);
        wv[half][6]=(short)f2bf(vb.z); wv[half][7]=(short)f2bf(vb.w);
    }
    const f32x4 zac = {0.f, 0.f, 0.f, 0.f};
    f32x4 ks0 = zac, ks1 = zac;
    #pragma unroll
    for (int sg = 0; sg < 4; ++sg) {
        const int sl = w*64 + sg*16 + m;
        const float* xp = x + (rowbase + sl)*C + head*DIM + g*8;
        float4 xa = *reinterpret_cast<const float4*>(xp);
        float4 xc = *reinterpret_cast<const float4*>(xp + 4);
        bf16x8 xf;
        xf[0]=(short)f2bf(xa.x); xf[1]=(short)f2bf(xa.y);
        xf[2]=(short)f2bf(xa.z); xf[3]=(short)f2bf(xa.w);
        xf[4]=(short)f2bf(xc.x); xf[5]=(short)f2bf(xc.y);
        xf[6]=(short)f2bf(xc.z); xf[7]=(short)f2bf(xc.w);
        f32x4 kt0 = __builtin_amdgcn_mfma_f32_16x16x32_bf16(wk[0], xf, zac, 0, 0, 0);
        f32x4 kt1 = __builtin_amdgcn_mfma_f32_16x16x32_bf16(wk[1], xf, zac, 0, 0, 0);
        f32x4 vt0 = __builtin_amdgcn_mfma_f32_16x16x32_bf16(wv[0], xf, zac, 0, 0, 0);
        f32x4 vt1 = __builtin_amdgcn_mfma_f32_16x16x32_bf16(wv[1], xf, zac, 0, 0, 0);
        #pragma unroll
        for (int r = 0; r < 4; ++r) {
            unsigned short u0 = f2bf(phi_elu1(kt0[r]));
            unsigned short u1 = f2bf(phi_elu1(kt1[r]));
            KsT[(4*g+r)*264 + sl]    = u0;
            KsT[(16+4*g+r)*264 + sl] = u1;
            ks0[r] += bf2f(u0);
            ks1[r] += bf2f(u1);
            VsT[(4*g+r)*264 + sl]    = f2bf(vt0[r]);
            VsT[(16+4*g+r)*264 + sl] = f2bf(vt1[r]);
        }
    }
    #pragma unroll
    for (int mk = 8; mk >= 1; mk >>= 1) {
        #pragma unroll
        for (int r = 0; r < 4; ++r) {
            ks0[r] += __shfl_xor(ks0[r], mk, 64);
            ks1[r] += __shfl_xor(ks1[r], mk, 64);
        }
    }
    if (m == 0) {
        #pragma unroll
        for (int r = 0; r < 4; ++r) {
            ksr[w][4*g + r]      = ks0[r];
            ksr[w][16 + 4*g + r] = ks1[r];
        }
    }
    __syncthreads();
    f32x4 acc[2][2] = {};
    #pragma unroll
    for (int ss = 0; ss < 2; ++ss) {
        const int s0 = w*64 + ss*32 + g*8;
        bf16x8 aK0 = *reinterpret_cast<const bf16x8*>(&KsT[m*264 + s0]);
        bf16x8 aK1 = *reinterpret_cast<const bf16x8*>(&KsT[(16+m)*264 + s0]);
        bf16x8 bV0 = *reinterpret_cast<const bf16x8*>(&VsT[m*264 + s0]);
        bf16x8 bV1 = *reinterpret_cast<const bf16x8*>(&VsT[(16+m)*264 + s0]);
        acc[0][0] = __builtin_amdgcn_mfma_f32_16x16x32_bf16(aK0, bV0, acc[0][0], 0, 0, 0);
        acc[0][1] = __builtin_amdgcn_mfma_f32_16x16x32_bf16(aK0, bV1, acc[0][1], 0, 0, 0);
        acc[1][0] = __builtin_amdgcn_mfma_f32_16x16x32_bf16(aK1, bV0, acc[1][0], 0, 0, 0);
        acc[1][1] = __builtin_amdgcn_mfma_f32_16x16x32_bf16(aK1, bV1, acc[1][1], 0, 0, 0);
    }
    #pragma unroll
    for (int i = 0; i < 2; ++i)
        #pragma unroll
        for (int j = 0; j < 2; ++j)
            #pragma unroll
            for (int r = 0; r < 4; ++r)
                red[w][i*16 + 4*g + r][j*16 + m] = acc[i][j][r];
    __syncthreads();
    float* pb = part + ((size_t)bh*NCHUNK + chunk)*1056;
    {
        const int d = t >> 3, e0 = (t & 7)*4;
        float4 sum;
        sum.x = red[0][d][e0+0]+red[1][d][e0+0]+red[2][d][e0+0]+red[3][d][e0+0];
        sum.y = red[0][d][e0+1]+red[1][d][e0+1]+red[2][d][e0+1]+red[3][d][e0+1];
        sum.z = red[0][d][e0+2]+red[1][d][e0+2]+red[2][d][e0+2]+red[3][d][e0+2];
        sum.w = red[0][d][e0+3]+red[1][d][e0+3]+red[2][d][e0+3]+red[3][d][e0+3];
        *reinterpret_cast<float4*>(pb + d*32 + e0) = sum;
    }
    if (t < 32) {
        pb[1024 + t] = ksr[0][t] + ksr[1][t] + ksr[2][t] + ksr[3][t];
    }
}

// ---------------- K2: deterministic reduce ----------------
__global__ __launch_bounds__(256) void k2_kv_reduce(
        const float* __restrict__ part, float* __restrict__ kv) {
    const int bh = blockIdx.x, t = threadIdx.x;
    for (int i = t; i < 1056; i += 256) {
        float s = 0.f;
        for (int c2 = 0; c2 < NCHUNK; ++c2)
            s += part[((size_t)bh*NCHUNK + c2)*1056 + i];
        kv[bh*1056 + i] = s;
    }
}

// ---------------- K3 (MFMA): Q-proj + attn, residual + LN1 -> xb ----------------
__global__ __launch_bounds__(256) void k3_attn_ln1_mfma(
        const float* __restrict__ x, const float* __restrict__ Wkqv,
        const float* __restrict__ kv, const float* __restrict__ g1,
        const float* __restrict__ be1, unsigned short* __restrict__ xb) {
    __shared__ __align__(16) unsigned short wq[32*40];
    __shared__ __align__(16) unsigned short kvt[NH*32*40];
    __shared__ __align__(16) float ksm[NH*32];
    __shared__ __align__(16) float gl[C], bl[C];
    __shared__ __align__(16) unsigned short qld[4][2][16*40];
    const int t = threadIdx.x;
    const int wid = t >> 6, lane = t & 63;
    const int g = lane >> 4, m = lane & 15;
    const int row0 = blockIdx.x * 64;
    const int b = row0 / LSEQ;
    for (int idx = t; idx < 1024; idx += 256) {
        int e = idx >> 5, d = idx & 31;
        wq[e*40 + d] = f2bf(Wkqv[1024 + idx]);
    }
    for (int idx = t; idx < NH*1024; idx += 256) {
        int h = idx >> 10, rem = idx & 1023;
        int d = rem >> 5, eo = rem & 31;
        kvt[h*1280 + eo*40 + d] = f2bf(kv[(size_t)(b*NH + h)*1056 + rem]);
    }
    {
        int h = t >> 5, d = t & 31;
        ksm[t] = kv[(size_t)(b*NH + h)*1056 + 1024 + d];
        gl[t] = g1[t];
        bl[t] = be1[t];
    }
    __syncthreads();

    const int row = row0 + wid*16 + m;
    f32x4 att[NH][2];
    const f32x4 zacc = {0.f, 0.f, 0.f, 0.f};
    #pragma unroll
    for (int h = 0; h < NH; ++h) {
        const float* xp = x + (size_t)row*C + h*32 + g*8;
        float4 xa = *reinterpret_cast<const float4*>(xp);
        float4 xc = *reinterpret_cast<const float4*>(xp + 4);
        bf16x8 xfrag;
        xfrag[0] = (short)f2bf(xa.x); xfrag[1] = (short)f2bf(xa.y);
        xfrag[2] = (short)f2bf(xa.z); xfrag[3] = (short)f2bf(xa.w);
        xfrag[4] = (short)f2bf(xc.x); xfrag[5] = (short)f2bf(xc.y);
        xfrag[6] = (short)f2bf(xc.z); xfrag[7] = (short)f2bf(xc.w);
        bf16x8 wf0 = *reinterpret_cast<const bf16x8*>(&wq[m*40 + g*8]);
        bf16x8 wf1 = *reinterpret_cast<const bf16x8*>(&wq[(16+m)*40 + g*8]);
        f32x4 q0 = __builtin_amdgcn_mfma_f32_16x16x32_bf16(wf0, xfrag, zacc, 0, 0, 0);
        f32x4 q1 = __builtin_amdgcn_mfma_f32_16x16x32_bf16(wf1, xfrag, zacc, 0, 0, 0);
        #pragma unroll
        for (int r = 0; r < 4; ++r) { q0[r] = phi_elu1(q0[r]); q1[r] = phi_elu1(q1[r]); }
        f32x4 ks0 = *reinterpret_cast<const f32x4*>(&ksm[h*32 + g*4]);
        f32x4 ks1 = *reinterpret_cast<const f32x4*>(&ksm[h*32 + 16 + g*4]);
        float zp = q0[0]*ks0[0] + q0[1]*ks0[1] + q0[2]*ks0[2] + q0[3]*ks0[3]
                 + q1[0]*ks1[0] + q1[1]*ks1[1] + q1[2]*ks1[2] + q1[3]*ks1[3];
        zp += __shfl_xor(zp, 16, 64);
        zp += __shfl_xor(zp, 32, 64);
        const float Z = 1.f / (zp + 1e-6f);
        unsigned short* slot = &qld[wid][h & 1][0];
        *reinterpret_cast<uint2*>(&slot[m*40 + g*4]) =
            make_uint2(pack2bf(q0[0], q0[1]), pack2bf(q0[2], q0[3]));
        *reinterpret_cast<uint2*>(&slot[m*40 + 16 + g*4]) =
            make_uint2(pack2bf(q1[0], q1[1]), pack2bf(q1[2], q1[3]));
        __builtin_amdgcn_wave_barrier();
        bf16x8 qrow = *reinterpret_cast<const bf16x8*>(&slot[m*40 + g*8]);
        __builtin_amdgcn_wave_barrier();
        bf16x8 kf0 = *reinterpret_cast<const bf16x8*>(&kvt[h*1280 + m*40 + g*8]);
        bf16x8 kf1 = *reinterpret_cast<const bf16x8*>(&kvt[h*1280 + (16+m)*40 + g*8]);
        f32x4 a0 = __builtin_amdgcn_mfma_f32_16x16x32_bf16(kf0, qrow, zacc, 0, 0, 0);
        f32x4 a1 = __builtin_amdgcn_mfma_f32_16x16x32_bf16(kf1, qrow, zacc, 0, 0, 0);
        #pragma unroll
        for (int r = 0; r < 4; ++r) { a0[r] *= Z; a1[r] *= Z; }
        att[h][0] = a0;
        att[h][1] = a1;
    }
    float s1 = 0.f, s2 = 0.f;
    #pragma unroll
    for (int h = 0; h < NH; ++h) {
        #pragma unroll
        for (int n = 0; n < 2; ++n) {
            const int c0 = h*32 + n*16 + g*4;
            float4 xr = *reinterpret_cast<const float4*>(x + (size_t)row*C + c0);
            f32x4 v = att[h][n];
            v[0] += xr.x; v[1] += xr.y; v[2] += xr.z; v[3] += xr.w;
            att[h][n] = v;
            s1 += v[0] + v[1] + v[2] + v[3];
            s2 += v[0]*v[0] + v[1]*v[1] + v[2]*v[2] + v[3]*v[3];
        }
    }
    s1 += __shfl_xor(s1, 16, 64); s1 += __shfl_xor(s1, 32, 64);
    s2 += __shfl_xor(s2, 16, 64); s2 += __shfl_xor(s2, 32, 64);
    const float mean = s1 * (1.f/C);
    const float var  = s2 * (1.f/C) - mean*mean;
    const float rs = rsqrtf(var + 1e-5f);
    #pragma unroll
    for (int h = 0; h < NH; ++h) {
        #pragma unroll
        for (int n = 0; n < 2; ++n) {
            const int c0 = h*32 + n*16 + g*4;
            f32x4 gv = *reinterpret_cast<const f32x4*>(&gl[c0]);
            f32x4 bv = *reinterpret_cast<const f32x4*>(&bl[c0]);
            f32x4 v = att[h][n];
            float o0 = (v[0]-mean)*rs*gv[0] + bv[0];
            float o1 = (v[1]-mean)*rs*gv[1] + bv[1];
            float o2 = (v[2]-mean)*rs*gv[2] + bv[2];
            float o3 = (v[3]-mean)*rs*gv[3] + bv[3];
            *reinterpret_cast<uint2*>(xb + (size_t)row*C + c0) =
                make_uint2(pack2bf(o0, o1), pack2bf(o2, o3));
        }
    }
}

// ---------------- K4: MFMA GEMM1, 128x128 tile, XCD swizzle, direct-store epilogue ----------------
// (r13's LDS-bounce epilogue regressed: added serialized LDS round-trip + extra
// barrier; the scalar stores were already 32B-segment coalesced and fire-and-forget.)
__global__ __launch_bounds__(256) void k4_ffn1_mfma(
        const unsigned short* __restrict__ A, const unsigned short* __restrict__ B,
        const float* __restrict__ b1, unsigned short* __restrict__ c1, int mbase) {
    __shared__ unsigned short As[128*64];
    __shared__ unsigned short Bs[128*64];
    const int t = threadIdx.x;
    const int wid = t >> 6, lane = t & 63;
    const int wr = wid >> 1, wc = wid & 1;
    const int chunkw = gridDim.x >> 3;                      // blocks per XCD
    const int swz = (blockIdx.x & 7) * chunkw + (blockIdx.x >> 3);
    const int rowp = swz >> 3, colb = swz & 7;
    const int m0 = mbase + rowp*128;
    const int n0 = colb*128;
    f32x4 acc[4][4] = {};
    for (int kt = 0; kt < C/64; ++kt) {
        const int k0 = kt*64;
        #pragma unroll
        for (int i = 0; i < 4; ++i) {
            const int seg = i*256 + t;
            const int row = seg >> 3, jd = seg & 7;
            const int js = jd ^ (row & 7);
            gload_lds16(A + (size_t)(m0+row)*C + k0 + js*8, &As[(i*256 + wid*64)*8]);
            gload_lds16(B + (size_t)(n0+row)*C + k0 + js*8, &Bs[(i*256 + wid*64)*8]);
        }
        __syncthreads();
        #pragma unroll
        for (int kk = 0; kk < 2; ++kk) {
            bf16x8 af[4], bfr[4];
            #pragma unroll
            for (int m = 0; m < 4; ++m) {
                const int row = wr*64 + m*16 + (lane & 15);
                const int j = (kk*4 + (lane >> 4)) ^ (row & 7);
                af[m] = *reinterpret_cast<const bf16x8*>(&As[row*64 + j*8]);
            }
            #pragma unroll
            for (int n = 0; n < 4; ++n) {
                const int row = wc*64 + n*16 + (lane & 15);
                const int j = (kk*4 + (lane >> 4)) ^ (row & 7);
                bfr[n] = *reinterpret_cast<const bf16x8*>(&Bs[row*64 + j*8]);
            }
            #pragma unroll
            for (int m = 0; m < 4; ++m)
                #pragma unroll
                for (int n = 0; n < 4; ++n)
                    acc[m][n] = __builtin_amdgcn_mfma_f32_16x16x32_bf16(af[m], bfr[n], acc[m][n], 0, 0, 0);
        }
        __syncthreads();
    }
    const int r4 = lane >> 4, cc = lane & 15;
    float b1v[4];
    #pragma unroll
    for (int n = 0; n < 4; ++n) b1v[n] = b1[n0 + wc*64 + n*16 + cc];
    #pragma unroll
    for (int m = 0; m < 4; ++m) {
        #pragma unroll
        for (int r = 0; r < 4; ++r) {
            const int lrow = rowp*128 + wr*64 + m*16 + r4*4 + r;   // c1-local
            #pragma unroll
            for (int n = 0; n < 4; ++n) {
                const int gcol = n0 + wc*64 + n*16 + cc;
                float f = acc[m][n][r] + b1v[n];
                c1[(size_t)lrow*FF + gcol] = f2bf(fast_gelu(f));
            }
        }
    }
}

// ---------------- K5: MFMA GEMM2 + residual + LN2 fused, 2-phase prefetch ----------------
__global__ __launch_bounds__(256) void k5_ffn2_ln(
        const unsigned short* __restrict__ A, const unsigned short* __restrict__ B,
        const float* __restrict__ b2, const unsigned short* __restrict__ xb,
        const float* __restrict__ g2, const float* __restrict__ be2,
        float* __restrict__ out, int mbase) {
    __shared__ __align__(16) unsigned short smem[40960];   // 80 KB
    unsigned short* As0 = smem;
    unsigned short* As1 = smem + 4096;
    unsigned short* Bs0 = smem + 8192;
    unsigned short* Bs1 = smem + 8192 + 16384;
    const int t = threadIdx.x;
    const int wid = t >> 6, lane = t & 63;
    const int lm0 = blockIdx.x*64;
    f32x4 acc[4][4] = {};

    #pragma unroll
    for (int i = 0; i < 2; ++i) {
        const int row = (i*256 + t) >> 3, jd = (i*256 + t) & 7;
        const int js = jd ^ (row & 7);
        gload_lds16(A + (size_t)(lm0+row)*FF + js*8, &As0[(i*256 + wid*64)*8]);
    }
    #pragma unroll
    for (int i = 0; i < 8; ++i) {
        const int row = (i*256 + t) >> 3, jd = (i*256 + t) & 7;
        const int js = jd ^ (row & 7);
        gload_lds16(B + (size_t)row*FF + js*8, &Bs0[(i*256 + wid*64)*8]);
    }
    __syncthreads();
    for (int kt = 0; kt < FF/64; ++kt) {
        const int cur = kt & 1;
        unsigned short* Asc = cur ? As1 : As0;
        unsigned short* Bsc = cur ? Bs1 : Bs0;
        if (kt < FF/64 - 1) {
            unsigned short* Asn = cur ? As0 : As1;
            unsigned short* Bsn = cur ? Bs0 : Bs1;
            const int k0n = (kt+1)*64;
            #pragma unroll
            for (int i = 0; i < 2; ++i) {
                const int row = (i*256 + t) >> 3, jd = (i*256 + t) & 7;
                const int js = jd ^ (row & 7);
                gload_lds16(A + (size_t)(lm0+row)*FF + k0n + js*8, &Asn[(i*256 + wid*64)*8]);
            }
            #pragma unroll
            for (int i = 0; i < 8; ++i) {
                const int row = (i*256 + t) >> 3, jd = (i*256 + t) & 7;
                const int js = jd ^ (row & 7);
                gload_lds16(B + (size_t)row*FF + k0n + js*8, &Bsn[(i*256 + wid*64)*8]);
            }
        }
        #pragma unroll
        for (int kk = 0; kk < 2; ++kk) {
            bf16x8 af[4], bfr[4];
            #pragma unroll
            for (int m = 0; m < 4; ++m) {
                const int row = m*16 + (lane & 15);
                const int j = (kk*4 + (lane >> 4)) ^ (row & 7);
                af[m] = *reinterpret_cast<const bf16x8*>(&Asc[row*64 + j*8]);
            }
            #pragma unroll
            for (int n = 0; n < 4; ++n) {
                const int row = wid*64 + n*16 + (lane & 15);
                const int j = (kk*4 + (lane >> 4)) ^ (row & 7);
                bfr[n] = *reinterpret_cast<const bf16x8*>(&Bsc[row*64 + j*8]);
            }
            #pragma unroll
            for (int m = 0; m < 4; ++m)
                #pragma unroll
                for (int n = 0; n < 4; ++n)
                    acc[m][n] = __builtin_amdgcn_mfma_f32_16x16x32_bf16(af[m], bfr[n], acc[m][n], 0, 0, 0);
        }
        if (kt < FF/64 - 1) __syncthreads();
    }
    float* red1 = (float*)smem;
    float* red2 = (float*)smem + 256;
    float* mear = (float*)smem + 512;
    float* rsr  = (float*)smem + 576;
    const int r4 = lane >> 4, cc = lane & 15;
    float b2v[4], g2v[4], be2v[4];
    #pragma unroll
    for (int n = 0; n < 4; ++n) {
        const int gcol = wid*64 + n*16 + cc;
        b2v[n] = b2[gcol]; g2v[n] = g2[gcol]; be2v[n] = be2[gcol];
    }
    float s1[4][4] = {}, s2[4][4] = {};
    #pragma unroll
    for (int m = 0; m < 4; ++m) {
        #pragma unroll
        for (int n = 0; n < 4; ++n) {
            const int gcol = wid*64 + n*16 + cc;
            #pragma unroll
            for (int r = 0; r < 4; ++r) {
                const size_t grow = (size_t)(mbase + lm0 + m*16 + r4*4 + r);
                float v = acc[m][n][r] + b2v[n] + bf2f(xb[grow*C + gcol]);
                acc[m][n][r] = v;
                s1[m][r] += v;
                s2[m][r] += v*v;
            }
        }
    }
    #pragma unroll
    for (int m = 0; m < 4; ++m) {
        #pragma unroll
        for (int r = 0; r < 4; ++r) {
            float a = s1[m][r], bb = s2[m][r];
            #pragma unroll
            for (int mk = 8; mk >= 1; mk >>= 1) {
                a  += __shfl_xor(a,  mk, 16);
                bb += __shfl_xor(bb, mk, 16);
            }
            if (cc == 0) {
                red1[wid*64 + m*16 + r4*4 + r] = a;
                red2[wid*64 + m*16 + r4*4 + r] = bb;
            }
        }
    }
    __syncthreads();
    if (t < 64) {
        float a  = red1[t]+red1[64+t]+red1[128+t]+red1[192+t];
        float bb = red2[t]+red2[64+t]+red2[128+t]+red2[192+t];
        float mean = a * (1.f/C);
        float var  = bb * (1.f/C) - mean*mean;
        mear[t] = mean;
        rsr[t]  = rsqrtf(var + 1e-5f);
    }
    __syncthreads();
    #pragma unroll
    for (int m = 0; m < 4; ++m) {
        #pragma unroll
        for (int r = 0; r < 4; ++r) {
            const int rl = m*16 + r4*4 + r;
            const float mu = mear[rl], rs = rsr[rl];
            const size_t grow = (size_t)(mbase + lm0 + rl);
            #pragma unroll
            for (int n = 0; n < 4; ++n) {
                const int gcol = wid*64 + n*16 + cc;
                out[grow*C + gcol] = (acc[m][n][r] - mu)*rs*g2v[n] + be2v[n];
            }
        }
    }
}

extern "C" void kernel_launch(void* const* d_in, const int* in_sizes, int n_in,
                              void* d_out, int out_size, void* d_ws, size_t ws_size,
                              hipStream_t stream) {
    const float* x    = (const float*)d_in[0];
    const float* Wkqv = (const float*)d_in[1];
    const float* W1   = (const float*)d_in[2];
    const float* b1   = (const float*)d_in[3];
    const float* W2   = (const float*)d_in[4];
    const float* b2   = (const float*)d_in[5];
    const float* g1   = (const float*)d_in[6];
    const float* be1  = (const float*)d_in[7];
    const float* g2   = (const float*)d_in[8];
    const float* be2  = (const float*)d_in[9];
    float* out = (float*)d_out;

    // ws layout (bytes):
    //   kv @ 0 | W1b @ 128K | W2b @ 640K | part @ 2M | xb @ 12M | c1 @ 48M
    // Full-M path needs 48M + ROWS*FF*2 = 176,160,768 B; else 2-chunk (111 MB).
    char* wsb = (char*)d_ws;
    float* kv            = (float*)(wsb);
    unsigned short* W1b  = (unsigned short*)(wsb + (131072));
    unsigned short* W2b  = (unsigned short*)(wsb + (655360));
    float* part          = (float*)(wsb + ((size_t)2 << 20));
    unsigned short* xb   = (unsigned short*)(wsb + ((size_t)12 << 20));
    unsigned short* c1   = (unsigned short*)(wsb + ((size_t)48 << 20));
    const size_t need_full = ((size_t)48 << 20) + (size_t)ROWS * FF * 2;

    k0_cvt<<<1024, 256, 0, stream>>>(W1, W2, W1b, W2b);
    k1_kv_partial_mfma<<<dim3(16, NCHUNK), 256, 0, stream>>>(x, Wkqv, part);
    k2_kv_reduce<<<16, 256, 0, stream>>>(part, kv);
    k3_attn_ln1_mfma<<<ROWS/64, 256, 0, stream>>>(x, Wkqv, kv, g1, be1, xb);
    if (ws_size >= need_full) {
        k4_ffn1_mfma<<<(ROWS/128)*(FF/128), 256, 0, stream>>>(xb, W1b, b1, c1, 0);
        k5_ffn2_ln<<<ROWS/64, 256, 0, stream>>>(c1, W2b, b2, xb, g2, be2, out, 0);
    } else {
        for (int chunk = 0; chunk < 2; ++chunk) {
            const int mbase = chunk * MCHUNK;
            k4_ffn1_mfma<<<(MCHUNK/128)*(FF/128), 256, 0, stream>>>(xb, W1b, b1, c1, mbase);
            k5_ffn2_ln<<<MCHUNK/64, 256, 0, stream>>>(c1, W2b, b2, xb, g2, be2, out, mbase);
        }
    }
}